// Round 3
// baseline (2374.555 us; speedup 1.0000x reference)
//
#include <hip/hip_runtime.h>

constexpr int N_NODES  = 500000;
constexpr int N_EDGES  = 8000000;
constexpr int N_GRAPHS = 25000;
constexpr int HID      = 19;

constexpr int NC    = (N_NODES + 1023) / 1024;   // 489 coarse buckets (dst>>10)
constexpr int NF    = NC * 16;                   // 7824 fine buckets of 64 nodes
constexpr int NFB   = (N_NODES + 63) / 64;       // 7813 fine buckets actually holding nodes
constexpr int P1B   = 256;                       // histogram blocks
constexpr int CHUNK = 8192;                      // edges per p2 block
constexpr int P2B   = (N_EDGES + CHUNK - 1) / CHUNK;  // 977

// ---------------- P1: per-block coarse histograms (no global atomics) ----------------
__global__ __launch_bounds__(256)
void p1_hist(const int* __restrict__ dst, int* __restrict__ blockhist) {
    __shared__ int h[NC];
    int t = threadIdx.x;
    for (int i = t; i < NC; i += 256) h[i] = 0;
    __syncthreads();
    int per = (N_EDGES + P1B - 1) / P1B;
    int s0 = blockIdx.x * per;
    int s1 = min(s0 + per, N_EDGES);
    for (int e = s0 + t; e < s1; e += 256) atomicAdd(&h[dst[e] >> 10], 1);
    __syncthreads();
    for (int i = t; i < NC; i += 256) blockhist[blockIdx.x * NC + i] = h[i];
}

// ---------------- K2: reduce block hists + exclusive scan -> coarse_off, cursor ----------------
__global__ __launch_bounds__(512)
void k2_scan(const int* __restrict__ blockhist, int* __restrict__ coarse_off,
             int* __restrict__ cursor, int* __restrict__ fine_off) {
    __shared__ int sh[512];
    int t = threadIdx.x;
    int s = 0;
    if (t < NC)
        for (int b = 0; b < P1B; ++b) s += blockhist[b * NC + t];
    sh[t] = s;
    for (int off = 1; off < 512; off <<= 1) {
        __syncthreads();
        int a = (t >= off) ? sh[t - off] : 0;
        __syncthreads();
        sh[t] += a;
    }
    __syncthreads();
    if (t < NC) { int excl = sh[t] - s; coarse_off[t] = excl; cursor[t] = excl; }
    if (t == 0) { coarse_off[NC] = N_EDGES; fine_off[NF] = N_EDGES; }
}

// ---------------- P2: chunked scatter into coarse buckets ----------------
// pack = src | (dst&1023)<<19   (src < 2^19, total 29 bits)
__global__ __launch_bounds__(256)
void p2_scatter(const int* __restrict__ src, const int* __restrict__ dst,
                int* __restrict__ cursor, int* __restrict__ bc) {
    __shared__ int h[NC], base[NC];
    int t = threadIdx.x;
    for (int i = t; i < NC; i += 256) h[i] = 0;
    __syncthreads();
    int e0 = blockIdx.x * CHUNK;
    int e1 = min(e0 + CHUNK, N_EDGES);
    for (int e = e0 + t; e < e1; e += 256) atomicAdd(&h[dst[e] >> 10], 1);
    __syncthreads();
    for (int i = t; i < NC; i += 256) {
        int c = h[i];
        base[i] = c ? atomicAdd(&cursor[i], c) : 0;
    }
    __syncthreads();
    for (int i = t; i < NC; i += 256) h[i] = 0;
    __syncthreads();
    for (int e = e0 + t; e < e1; e += 256) {
        int d = dst[e];
        int cb = d >> 10;
        int r = atomicAdd(&h[cb], 1);
        bc[base[cb] + r] = src[e] | ((d & 1023) << 19);
    }
}

// ---------------- P3: split each coarse bucket into 16 fine (64-node) buckets ----------------
__global__ __launch_bounds__(256)
void p3_split(const int* __restrict__ coarse_off, const int* __restrict__ bc,
              int* __restrict__ fine_off, int* __restrict__ bf) {
    int c = blockIdx.x;
    int b0 = coarse_off[c], b1 = coarse_off[c + 1];
    __shared__ int h[16], cur[16];
    int t = threadIdx.x;
    if (t < 16) h[t] = 0;
    __syncthreads();
    for (int i = b0 + t; i < b1; i += 256) atomicAdd(&h[(bc[i] >> 25) & 15], 1);
    __syncthreads();
    if (t == 0) {
        int a = 0;
        for (int f = 0; f < 16; ++f) { int cc = h[f]; h[f] = a; a += cc; }
    }
    __syncthreads();
    if (t < 16) { cur[t] = h[t]; fine_off[c * 16 + t] = b0 + h[t]; }
    __syncthreads();
    for (int i = b0 + t; i < b1; i += 256) {
        int v = bc[i];
        int f = (v >> 25) & 15;
        int r = atomicAdd(&cur[f], 1);
        bf[b0 + r] = v;
    }
}

// ---------------- combined weights: wc = w0 @ w1[IN:], db = b0 @ w1[IN:] ----------------
__global__ __launch_bounds__(256)
void weights_kernel(const float* w0_1, const float* b0_1, const float* w1_1,
                    const float* w0_2, const float* b0_2, const float* w1_2,
                    const float* w0_3, const float* b0_3, const float* w1_3,
                    float* __restrict__ out) {   // 3 layers * 380 floats (361 wc + 19 db)
    const float *w0, *b0, *w1; int IN;
    if (blockIdx.x == 0)      { w0 = w0_1; b0 = b0_1; w1 = w1_1; IN = 11; }
    else if (blockIdx.x == 1) { w0 = w0_2; b0 = b0_2; w1 = w1_2; IN = 19; }
    else                      { w0 = w0_3; b0 = b0_3; w1 = w1_3; IN = 19; }
    __shared__ float sw0[19 * 19], sw1b[19 * 19], sb0[19];
    int t = threadIdx.x;
    for (int i = t; i < IN * 19; i += 256) sw0[i]  = w0[i];
    for (int i = t; i < 19 * 19; i += 256) sw1b[i] = w1[IN * 19 + i];
    if (t < 19) sb0[t] = b0[t];
    __syncthreads();
    float* o = out + blockIdx.x * 380;
    for (int idx = t; idx < IN * 19; idx += 256) {
        int i = idx / 19, j = idx - 19 * (idx / 19);
        float s = 0.f;
        #pragma unroll
        for (int k = 0; k < 19; ++k) s = fmaf(sw0[i * 19 + k], sw1b[k * 19 + j], s);
        o[idx] = s;
    }
    if (t < 19) {
        float s = 0.f;
        #pragma unroll
        for (int k = 0; k < 19; ++k) s = fmaf(sb0[k], sw1b[k * 19 + t], s);
        o[361 + t] = s;
    }
}

// ---------------- fused layer over one 64-node fine bucket ----------------
// out = relu(x@w1a + (S@x)@wc + deg*db + b1 [+ x])
template<int IN, bool RES>
__global__ __launch_bounds__(256)
void layer_kernel(const float* __restrict__ x, const int* __restrict__ bf,
                  const int* __restrict__ fine_off,
                  const float* __restrict__ w1, const float* __restrict__ b1,
                  const float* __restrict__ wcdb, float* __restrict__ out) {
    __shared__ float acc[64][19];
    __shared__ float sx[64 * 19];
    __shared__ int   sdeg[64];
    __shared__ float sw1a[IN * 19], swc[IN * 19], sdb[19], sb1[19];
    int t = threadIdx.x;
    int nb = blockIdx.x;
    int node0 = nb * 64;
    int nn = min(64, N_NODES - node0);

    for (int i = t; i < IN * 19; i += 256) { sw1a[i] = w1[i]; swc[i] = wcdb[i]; }
    if (t < 19) { sdb[t] = wcdb[361 + t]; sb1[t] = b1[t]; }
    for (int i = t; i < 64 * 19; i += 256) ((float*)acc)[i] = 0.f;
    if (t < 64) sdeg[t] = 0;
    for (int i = t; i < nn * IN; i += 256) sx[i] = x[(size_t)node0 * IN + i];
    __syncthreads();

    int e0 = fine_off[nb], e1 = fine_off[nb + 1];
    int g = t / 19, c = t - g * 19;     // 13 edge-groups of 19 lanes
    if (t < 247) {
        for (int i = e0 + g; i < e1; i += 13) {
            int v = bf[i];
            int s = v & 0x7FFFF;
            int ld = (v >> 19) & 63;
            if (c < IN) atomicAdd(&acc[ld][c], x[(size_t)s * IN + c]);
            if (c == 0) atomicAdd(&sdeg[ld], 1);
        }
    }
    __syncthreads();

    for (int idx = t; idx < nn * 19; idx += 256) {
        int nl = idx / 19, cc = idx - nl * 19;
        float v = sb1[cc] + (float)sdeg[nl] * sdb[cc];
        #pragma unroll
        for (int i = 0; i < IN; ++i) v = fmaf(sx[nl * IN + i], sw1a[i * 19 + cc], v);
        #pragma unroll
        for (int i = 0; i < IN; ++i) v = fmaf(acc[nl][i], swc[i * 19 + cc], v);
        if (RES) v += sx[nl * 19 + cc];
        out[(size_t)(node0 + nl) * 19 + cc] = fmaxf(v, 0.f);
    }
}

// ---------------- pos[g] = last node index of graph g ----------------
__global__ __launch_bounds__(256)
void pos_kernel(const int* __restrict__ batch, int* __restrict__ pos) {
    int i = blockIdx.x * 256 + threadIdx.x;
    if (i >= N_NODES) return;
    int b  = batch[i];
    int nb = (i == N_NODES - 1) ? N_GRAPHS : batch[i + 1];
    for (int g = b; g < nb; ++g) pos[g] = i;
    if (i == 0) {
        for (int g = 0; g < b; ++g) pos[g] = N_NODES - 1;   // JAX -1 wrap
    }
}

// ---------------- readout ----------------
__global__ __launch_bounds__(256)
void readout_kernel(const float* __restrict__ h, const int* __restrict__ pos,
                    const float* __restrict__ w0, const float* __restrict__ b0,
                    const float* __restrict__ w1, const float* __restrict__ b1,
                    float* __restrict__ out) {
    __shared__ float ws[HID * 10 + 10 + 10 + 1];
    for (int i = threadIdx.x; i < 211; i += 256) {
        float v;
        if (i < 190)      v = w0[i];
        else if (i < 200) v = b0[i - 190];
        else if (i < 210) v = w1[i - 200];
        else              v = b1[0];
        ws[i] = v;
    }
    __syncthreads();
    int g = blockIdx.x * 256 + threadIdx.x;
    if (g >= N_GRAPHS) return;
    const float* hp = h + (size_t)pos[g] * HID;
    float t[10];
    #pragma unroll
    for (int j = 0; j < 10; ++j) {
        float acc = ws[190 + j];
        #pragma unroll
        for (int i = 0; i < HID; ++i) acc = fmaf(hp[i], ws[i * 10 + j], acc);
        t[j] = fmaxf(acc, 0.0f);
    }
    float o = ws[210];
    #pragma unroll
    for (int j = 0; j < 10; ++j) o = fmaf(t[j], ws[200 + j], o);
    out[g] = fmaxf(o, 0.0f);
}

extern "C" void kernel_launch(void* const* d_in, const int* in_sizes, int n_in,
                              void* d_out, int out_size, void* d_ws, size_t ws_size,
                              hipStream_t stream) {
    const float* x     = (const float*)d_in[0];
    const int*   ei    = (const int*)d_in[1];
    const int*   batch = (const int*)d_in[2];
    const float* w0_1 = (const float*)d_in[3];
    const float* b0_1 = (const float*)d_in[4];
    const float* w1_1 = (const float*)d_in[5];
    const float* b1_1 = (const float*)d_in[6];
    const float* w0_2 = (const float*)d_in[7];
    const float* b0_2 = (const float*)d_in[8];
    const float* w1_2 = (const float*)d_in[9];
    const float* b1_2 = (const float*)d_in[10];
    const float* w0_3 = (const float*)d_in[11];
    const float* b0_3 = (const float*)d_in[12];
    const float* w1_3 = (const float*)d_in[13];
    const float* b1_3 = (const float*)d_in[14];
    const float* wfc0 = (const float*)d_in[15];
    const float* bfc0 = (const float*)d_in[16];
    const float* wfc1 = (const float*)d_in[17];
    const float* bfc1 = (const float*)d_in[18];

    const int* src = ei;            // edge_index[0]
    const int* dst = ei + N_EDGES;  // edge_index[1]

    char* ws = (char*)d_ws;
    size_t off = 0;
    auto alloc = [&](size_t bytes) { void* p = ws + off; off = (off + bytes + 511) & ~(size_t)511; return p; };
    float* BUF_A     = (float*)alloc((size_t)N_NODES * HID * 4);   // 38 MB
    float* BUF_B     = (float*)alloc((size_t)N_NODES * HID * 4);   // 38 MB
    int*   bf        = (int*)  alloc((size_t)N_EDGES * 4);         // 32 MB (fine-bucketed packs)
    int*   blockhist = (int*)  alloc((size_t)P1B * NC * 4);        // 0.5 MB
    int*   coarse_off= (int*)  alloc((NC + 1) * 4);
    int*   cursor    = (int*)  alloc(NC * 4);
    int*   fine_off  = (int*)  alloc((NF + 1) * 4);
    int*   pos       = (int*)  alloc((size_t)N_GRAPHS * 4);
    float* wcdb      = (float*)alloc(3 * 380 * 4);
    // coarse-bucketed packs are dead before layer 1 writes BUF_A -> alias
    int*   bc        = (int*)BUF_A;                                // 32 MB alias

    dim3 blk(256);
    int gridN = (N_NODES + 255) / 256;
    int gridG = (N_GRAPHS + 255) / 256;

    weights_kernel<<<3, blk, 0, stream>>>(w0_1, b0_1, w1_1, w0_2, b0_2, w1_2,
                                          w0_3, b0_3, w1_3, wcdb);
    pos_kernel<<<gridN, blk, 0, stream>>>(batch, pos);

    // ---- bucket sort: coarse (489) then fine (64-node) ----
    p1_hist<<<P1B, blk, 0, stream>>>(dst, blockhist);
    k2_scan<<<1, 512, 0, stream>>>(blockhist, coarse_off, cursor, fine_off);
    p2_scatter<<<P2B, blk, 0, stream>>>(src, dst, cursor, bc);
    p3_split<<<NC, blk, 0, stream>>>(coarse_off, bc, fine_off, bf);

    // ---- 3 fused layers (one block per 64-node fine bucket) ----
    layer_kernel<11, false><<<NFB, blk, 0, stream>>>(x,     bf, fine_off, w1_1, b1_1, wcdb,       BUF_A);
    layer_kernel<19, true ><<<NFB, blk, 0, stream>>>(BUF_A, bf, fine_off, w1_2, b1_2, wcdb + 380, BUF_B);
    layer_kernel<19, true ><<<NFB, blk, 0, stream>>>(BUF_B, bf, fine_off, w1_3, b1_3, wcdb + 760, BUF_A);

    // ---- Readout ----
    readout_kernel<<<gridG, blk, 0, stream>>>(BUF_A, pos, wfc0, bfc0, wfc1, bfc1,
                                              (float*)d_out);
}

// Round 4
// 949.020 us; speedup vs baseline: 2.5021x; 2.5021x over previous
//
#include <hip/hip_runtime.h>

constexpr int N_NODES  = 500000;
constexpr int N_EDGES  = 8000000;
constexpr int N_GRAPHS = 25000;
constexpr int HID      = 19;

constexpr int NC    = (N_NODES + 1023) / 1024;   // 489 coarse buckets (dst>>10)
constexpr int P1B   = 256;                       // histogram blocks
constexpr int CHUNK = 8192;                      // edges per p2 block
constexpr int P2B   = (N_EDGES + CHUNK - 1) / CHUNK;  // 977
constexpr int NPB   = 13;                        // nodes per 256-thread block (13*19=247)

// ---------------- P1: per-block coarse histograms (no global atomics) ----------------
__global__ __launch_bounds__(256)
void p1_hist(const int* __restrict__ dst, int* __restrict__ blockhist) {
    __shared__ int h[NC];
    int t = threadIdx.x;
    for (int i = t; i < NC; i += 256) h[i] = 0;
    __syncthreads();
    int per = (N_EDGES + P1B - 1) / P1B;
    int s0 = blockIdx.x * per;
    int s1 = min(s0 + per, N_EDGES);
    for (int e = s0 + t; e < s1; e += 256) atomicAdd(&h[dst[e] >> 10], 1);
    __syncthreads();
    for (int i = t; i < NC; i += 256) blockhist[blockIdx.x * NC + i] = h[i];
}

// ---------------- K2: reduce block hists + exclusive scan -> coarse_off, cursor ----------------
__global__ __launch_bounds__(512)
void k2_scan(const int* __restrict__ blockhist, int* __restrict__ coarse_off,
             int* __restrict__ cursor, int* __restrict__ offsets) {
    __shared__ int sh[512];
    int t = threadIdx.x;
    int s = 0;
    if (t < NC)
        for (int b = 0; b < P1B; ++b) s += blockhist[b * NC + t];
    sh[t] = s;
    for (int off = 1; off < 512; off <<= 1) {
        __syncthreads();
        int a = (t >= off) ? sh[t - off] : 0;
        __syncthreads();
        sh[t] += a;
    }
    __syncthreads();
    if (t < NC) { int excl = sh[t] - s; coarse_off[t] = excl; cursor[t] = excl; }
    if (t == 0) { coarse_off[NC] = N_EDGES; offsets[N_NODES] = N_EDGES; }
}

// ---------------- P2: chunked scatter into coarse buckets ----------------
// pack = src | (dst&1023)<<19   (src < 2^19, total 29 bits)
__global__ __launch_bounds__(256)
void p2_scatter(const int* __restrict__ src, const int* __restrict__ dst,
                int* __restrict__ cursor, int* __restrict__ bc) {
    __shared__ int h[NC], base[NC];
    int t = threadIdx.x;
    for (int i = t; i < NC; i += 256) h[i] = 0;
    __syncthreads();
    int e0 = blockIdx.x * CHUNK;
    int e1 = min(e0 + CHUNK, N_EDGES);
    for (int e = e0 + t; e < e1; e += 256) atomicAdd(&h[dst[e] >> 10], 1);
    __syncthreads();
    for (int i = t; i < NC; i += 256) {
        int c = h[i];
        base[i] = c ? atomicAdd(&cursor[i], c) : 0;
    }
    __syncthreads();
    for (int i = t; i < NC; i += 256) h[i] = 0;
    __syncthreads();
    for (int e = e0 + t; e < e1; e += 256) {
        int d = dst[e];
        int cb = d >> 10;
        int r = atomicAdd(&h[cb], 1);
        bc[base[cb] + r] = src[e] | ((d & 1023) << 19);
    }
}

// ---------------- P3: node-exact CSR within each coarse bucket ----------------
__global__ __launch_bounds__(256)
void p3_csr(const int* __restrict__ coarse_off, const int* __restrict__ bc,
            int* __restrict__ offsets, int* __restrict__ csr) {
    int c = blockIdx.x;
    int b0 = coarse_off[c], b1 = coarse_off[c + 1];
    __shared__ int h[1024], cur[1024], ts[256];
    int t = threadIdx.x;
    for (int i = t; i < 1024; i += 256) h[i] = 0;
    __syncthreads();
    for (int i = b0 + t; i < b1; i += 256) atomicAdd(&h[(bc[i] >> 19) & 1023], 1);
    __syncthreads();
    // exclusive scan of h[1024]: 4 per thread + block scan
    int base4 = t * 4;
    int a0 = h[base4], a1 = h[base4 + 1], a2 = h[base4 + 2], a3 = h[base4 + 3];
    int s = a0 + a1 + a2 + a3;
    ts[t] = s;
    for (int off = 1; off < 256; off <<= 1) {
        __syncthreads();
        int v = (t >= off) ? ts[t - off] : 0;
        __syncthreads();
        ts[t] += v;
    }
    __syncthreads();
    int excl = ts[t] - s;
    h[base4]     = excl;
    h[base4 + 1] = excl + a0;
    h[base4 + 2] = excl + a0 + a1;
    h[base4 + 3] = excl + a0 + a1 + a2;
    cur[base4]     = h[base4];
    cur[base4 + 1] = h[base4 + 1];
    cur[base4 + 2] = h[base4 + 2];
    cur[base4 + 3] = h[base4 + 3];
    __syncthreads();
    int node0 = c << 10;
    for (int i = t; i < 1024; i += 256) {
        int n = node0 + i;
        if (n < N_NODES) offsets[n] = b0 + h[i];
    }
    for (int i = b0 + t; i < b1; i += 256) {
        int v = bc[i];
        int loc = (v >> 19) & 1023;
        int p = atomicAdd(&cur[loc], 1);
        csr[b0 + p] = v & 0x7FFFF;
    }
}

// ---------------- combined weights: wc = w0 @ w1[IN:], db = b0 @ w1[IN:] ----------------
__global__ __launch_bounds__(256)
void weights_kernel(const float* w0_1, const float* b0_1, const float* w1_1,
                    const float* w0_2, const float* b0_2, const float* w1_2,
                    const float* w0_3, const float* b0_3, const float* w1_3,
                    float* __restrict__ out) {   // 3 layers * 380 floats (361 wc + 19 db)
    const float *w0, *b0, *w1; int IN;
    if (blockIdx.x == 0)      { w0 = w0_1; b0 = b0_1; w1 = w1_1; IN = 11; }
    else if (blockIdx.x == 1) { w0 = w0_2; b0 = b0_2; w1 = w1_2; IN = 19; }
    else                      { w0 = w0_3; b0 = b0_3; w1 = w1_3; IN = 19; }
    __shared__ float sw0[19 * 19], sw1b[19 * 19], sb0[19];
    int t = threadIdx.x;
    for (int i = t; i < IN * 19; i += 256) sw0[i]  = w0[i];
    for (int i = t; i < 19 * 19; i += 256) sw1b[i] = w1[IN * 19 + i];
    if (t < 19) sb0[t] = b0[t];
    __syncthreads();
    float* o = out + blockIdx.x * 380;
    for (int idx = t; idx < IN * 19; idx += 256) {
        int i = idx / 19, j = idx - 19 * (idx / 19);
        float s = 0.f;
        #pragma unroll
        for (int k = 0; k < 19; ++k) s = fmaf(sw0[i * 19 + k], sw1b[k * 19 + j], s);
        o[idx] = s;
    }
    if (t < 19) {
        float s = 0.f;
        #pragma unroll
        for (int k = 0; k < 19; ++k) s = fmaf(sb0[k], sw1b[k * 19 + t], s);
        o[361 + t] = s;
    }
}

// ---------------- fused layer: out = relu(x@w1a + (S@x)@wc + deg*db + b1 [+ x]) ----------------
template<int IN, bool RES>
__global__ __launch_bounds__(256)
void fused_layer(const float* __restrict__ x, const int* __restrict__ csr,
                 const int* __restrict__ offsets,
                 const float* __restrict__ w1, const float* __restrict__ b1,
                 const float* __restrict__ wcdb, float* __restrict__ out) {
    __shared__ float sw1a[IN * 19], swc[IN * 19], sdb[19], sb1[19];
    __shared__ float shx[NPB][19], shs[NPB][19];
    int t = threadIdx.x;
    for (int i = t; i < IN * 19; i += 256) sw1a[i] = w1[i];
    for (int i = t; i < IN * 19; i += 256) swc[i]  = wcdb[i];
    if (t < 19) { sdb[t] = wcdb[361 + t]; sb1[t] = b1[t]; }
    __syncthreads();
    int g = t / 19, c = t - g * 19;
    int n = blockIdx.x * NPB + g;
    bool active = (t < NPB * 19) && (n < N_NODES);
    int o0 = 0, o1 = 0;
    if (active) {
        o0 = offsets[n]; o1 = offsets[n + 1];
        float xr = 0.f, acc = 0.f;
        if (c < IN) {
            xr = x[(size_t)n * IN + c];
            int i = o0;
            for (; i + 1 < o1; i += 2) {
                int s0 = csr[i], s1 = csr[i + 1];
                acc += x[(size_t)s0 * IN + c] + x[(size_t)s1 * IN + c];
            }
            if (i < o1) acc += x[(size_t)csr[i] * IN + c];
        }
        shx[g][c] = xr; shs[g][c] = acc;
    }
    __syncthreads();
    if (active) {
        float v = sb1[c] + (float)(o1 - o0) * sdb[c];
        #pragma unroll
        for (int i = 0; i < IN; ++i) v = fmaf(shx[g][i], sw1a[i * 19 + c], v);
        #pragma unroll
        for (int i = 0; i < IN; ++i) v = fmaf(shs[g][i], swc[i * 19 + c], v);
        if (RES) v += shx[g][c];
        out[(size_t)n * 19 + c] = fmaxf(v, 0.f);
    }
}

// ---------------- pos[g] = last node index of graph g ----------------
__global__ __launch_bounds__(256)
void pos_kernel(const int* __restrict__ batch, int* __restrict__ pos) {
    int i = blockIdx.x * 256 + threadIdx.x;
    if (i >= N_NODES) return;
    int b  = batch[i];
    int nb = (i == N_NODES - 1) ? N_GRAPHS : batch[i + 1];
    for (int g = b; g < nb; ++g) pos[g] = i;
    if (i == 0) {
        for (int g = 0; g < b; ++g) pos[g] = N_NODES - 1;   // JAX -1 wrap
    }
}

// ---------------- readout ----------------
__global__ __launch_bounds__(256)
void readout_kernel(const float* __restrict__ h, const int* __restrict__ pos,
                    const float* __restrict__ w0, const float* __restrict__ b0,
                    const float* __restrict__ w1, const float* __restrict__ b1,
                    float* __restrict__ out) {
    __shared__ float ws[HID * 10 + 10 + 10 + 1];
    for (int i = threadIdx.x; i < 211; i += 256) {
        float v;
        if (i < 190)      v = w0[i];
        else if (i < 200) v = b0[i - 190];
        else if (i < 210) v = w1[i - 200];
        else              v = b1[0];
        ws[i] = v;
    }
    __syncthreads();
    int g = blockIdx.x * 256 + threadIdx.x;
    if (g >= N_GRAPHS) return;
    const float* hp = h + (size_t)pos[g] * HID;
    float t[10];
    #pragma unroll
    for (int j = 0; j < 10; ++j) {
        float acc = ws[190 + j];
        #pragma unroll
        for (int i = 0; i < HID; ++i) acc = fmaf(hp[i], ws[i * 10 + j], acc);
        t[j] = fmaxf(acc, 0.0f);
    }
    float o = ws[210];
    #pragma unroll
    for (int j = 0; j < 10; ++j) o = fmaf(t[j], ws[200 + j], o);
    out[g] = fmaxf(o, 0.0f);
}

extern "C" void kernel_launch(void* const* d_in, const int* in_sizes, int n_in,
                              void* d_out, int out_size, void* d_ws, size_t ws_size,
                              hipStream_t stream) {
    const float* x     = (const float*)d_in[0];
    const int*   ei    = (const int*)d_in[1];
    const int*   batch = (const int*)d_in[2];
    const float* w0_1 = (const float*)d_in[3];
    const float* b0_1 = (const float*)d_in[4];
    const float* w1_1 = (const float*)d_in[5];
    const float* b1_1 = (const float*)d_in[6];
    const float* w0_2 = (const float*)d_in[7];
    const float* b0_2 = (const float*)d_in[8];
    const float* w1_2 = (const float*)d_in[9];
    const float* b1_2 = (const float*)d_in[10];
    const float* w0_3 = (const float*)d_in[11];
    const float* b0_3 = (const float*)d_in[12];
    const float* w1_3 = (const float*)d_in[13];
    const float* b1_3 = (const float*)d_in[14];
    const float* wfc0 = (const float*)d_in[15];
    const float* bfc0 = (const float*)d_in[16];
    const float* wfc1 = (const float*)d_in[17];
    const float* bfc1 = (const float*)d_in[18];

    const int* src = ei;            // edge_index[0]
    const int* dst = ei + N_EDGES;  // edge_index[1]

    char* ws = (char*)d_ws;
    size_t off = 0;
    auto alloc = [&](size_t bytes) { void* p = ws + off; off = (off + bytes + 511) & ~(size_t)511; return p; };
    float* BUF_A     = (float*)alloc((size_t)N_NODES * HID * 4);   // 38 MB
    float* BUF_B     = (float*)alloc((size_t)N_NODES * HID * 4);   // 38 MB
    int*   csr       = (int*)  alloc((size_t)N_EDGES * 4);         // 32 MB
    int*   offsets   = (int*)  alloc(((size_t)N_NODES + 1) * 4);
    int*   blockhist = (int*)  alloc((size_t)P1B * NC * 4);        // 0.5 MB
    int*   coarse_off= (int*)  alloc((NC + 1) * 4);
    int*   cursor    = (int*)  alloc(NC * 4);
    int*   pos       = (int*)  alloc((size_t)N_GRAPHS * 4);
    float* wcdb      = (float*)alloc(3 * 380 * 4);
    // coarse-bucketed packs dead before layer 1 writes BUF_A -> alias
    int*   bc        = (int*)BUF_A;                                // 32 MB alias

    dim3 blk(256);
    int gridN = (N_NODES + 255) / 256;
    int gridF = (N_NODES + NPB - 1) / NPB;   // 38462
    int gridG = (N_GRAPHS + 255) / 256;

    weights_kernel<<<3, blk, 0, stream>>>(w0_1, b0_1, w1_1, w0_2, b0_2, w1_2,
                                          w0_3, b0_3, w1_3, wcdb);
    pos_kernel<<<gridN, blk, 0, stream>>>(batch, pos);

    // ---- bucket sort -> node-exact CSR ----
    p1_hist<<<P1B, blk, 0, stream>>>(dst, blockhist);
    k2_scan<<<1, 512, 0, stream>>>(blockhist, coarse_off, cursor, offsets);
    p2_scatter<<<P2B, blk, 0, stream>>>(src, dst, cursor, bc);
    p3_csr<<<NC, blk, 0, stream>>>(coarse_off, bc, offsets, csr);

    // ---- 3 fused layers (register-accumulated CSR walk) ----
    fused_layer<11, false><<<gridF, blk, 0, stream>>>(x,     csr, offsets, w1_1, b1_1, wcdb,       BUF_A);
    fused_layer<19, true ><<<gridF, blk, 0, stream>>>(BUF_A, csr, offsets, w1_2, b1_2, wcdb + 380, BUF_B);
    fused_layer<19, true ><<<gridF, blk, 0, stream>>>(BUF_B, csr, offsets, w1_3, b1_3, wcdb + 760, BUF_A);

    // ---- Readout ----
    readout_kernel<<<gridG, blk, 0, stream>>>(BUF_A, pos, wfc0, bfc0, wfc1, bfc1,
                                              (float*)d_out);
}